// Round 9
// baseline (358.959 us; speedup 1.0000x reference)
//
#include <hip/hip_runtime.h>
#include <hip/hip_bf16.h>

#define BB 4
#define CC 256
#define NN 4096
#define AC2 64
#define PP 72   // LDS pitch (shorts): 144 B rows, 16B-aligned, reads spread 8 banks
#define JT 32   // j-tiles per out-block (j-split 2)
#define LOG2E 1.4426950408889634f

typedef __attribute__((ext_vector_type(4))) float f32x4;
typedef __attribute__((ext_vector_type(8))) short bf16x8;

__device__ __forceinline__ short f2bf(float f) {
    unsigned u = __builtin_bit_cast(unsigned, f);
    u = u + 0x7FFFu + ((u >> 16) & 1u);
    return (short)(u >> 16);
}
__device__ __forceinline__ float bf2f(unsigned short h) {
    unsigned u = ((unsigned)h) << 16;
    return __builtin_bit_cast(float, u);
}

// ---------------- Kernel 0: convert weights to bf16 Wb[384][256] ----------------
__global__ __launch_bounds__(256) void prep_kernel(
    const float* __restrict__ Wq, const float* __restrict__ Wk,
    const float* __restrict__ Wv, short* __restrict__ Wb)
{
    const int idx = (blockIdx.x * 256 + threadIdx.x) * 4;  // 96 blocks cover 98304
    const int o = idx >> 8, c = idx & 255;
    const float* row = (o < 64) ? (Wq + o * CC)
                     : (o < 128) ? (Wk + (o - 64) * CC)
                                 : (Wv + (o - 128) * CC);
    float4 v = *(const float4*)&row[c];
    short4 s4;
    s4.x = f2bf(v.x); s4.y = f2bf(v.y); s4.z = f2bf(v.z); s4.w = f2bf(v.w);
    *(short4*)&Wb[idx] = s4;
}

// ---------------- Kernel 1: QKV projection ----------------
// Q outputs (o<64) scaled by log2e so downstream softmax uses exp2 directly.
__global__ __launch_bounds__(512) void qkv_kernel(
    const float* __restrict__ x, const short* __restrict__ Wb,
    const float* __restrict__ bq, const float* __restrict__ bk,
    const float* __restrict__ bv,
    short* __restrict__ Qt, short* __restrict__ Kt, short* __restrict__ V)
{
    __shared__ __align__(16) short Xl[32 * 72];
    const int bid0 = blockIdx.x;                 // grid 512
    const int xcd = bid0 & 7;
    const int b = xcd >> 1, nh = xcd & 1;
    const int n0 = (nh * 64 + (bid0 >> 3)) << 5; // n-tile of 32
    const int tid = threadIdx.x;
    const int lane = tid & 63, w = tid >> 6;
    const int l15 = lane & 15, lh = lane >> 4;

    f32x4 acc[3][2];
#pragma unroll
    for (int i = 0; i < 3; ++i)
#pragma unroll
        for (int j = 0; j < 2; ++j) acc[i][j] = (f32x4){0.f, 0.f, 0.f, 0.f};

    for (int ck = 0; ck < 4; ++ck) {
        const int c0 = ck << 6;
        bf16x8 Af[3][2];
#pragma unroll
        for (int of = 0; of < 3; ++of)
#pragma unroll
            for (int ks = 0; ks < 2; ++ks)
                Af[of][ks] = *(const bf16x8*)&Wb[(size_t)(w * 48 + of * 16 + l15) * CC +
                                                 c0 + ks * 32 + (lh << 3)];
        {
            const int cr = tid >> 3, q4 = tid & 7;
            float4 v = *(const float4*)&x[((size_t)(b * CC + c0 + cr)) * NN + n0 + q4 * 4];
            Xl[(q4 * 4 + 0) * 72 + cr] = f2bf(v.x);
            Xl[(q4 * 4 + 1) * 72 + cr] = f2bf(v.y);
            Xl[(q4 * 4 + 2) * 72 + cr] = f2bf(v.z);
            Xl[(q4 * 4 + 3) * 72 + cr] = f2bf(v.w);
        }
        __syncthreads();
#pragma unroll
        for (int ks = 0; ks < 2; ++ks) {
            const int co = ks * 32 + (lh << 3);
            bf16x8 Bf[2];
#pragma unroll
            for (int nf = 0; nf < 2; ++nf)
                Bf[nf] = *(const bf16x8*)&Xl[(nf * 16 + l15) * 72 + co];
#pragma unroll
            for (int of = 0; of < 3; ++of)
#pragma unroll
                for (int nf = 0; nf < 2; ++nf)
                    acc[of][nf] = __builtin_amdgcn_mfma_f32_16x16x32_bf16(
                        Af[of][ks], Bf[nf], acc[of][nf], 0, 0, 0);
        }
        __syncthreads();
    }
#pragma unroll
    for (int of = 0; of < 3; ++of) {
        const int obase = w * 48 + of * 16 + (lh << 2);
        float bias[4];
#pragma unroll
        for (int r = 0; r < 4; ++r) {
            int o = obase + r;
            bias[r] = (o < 64) ? bq[o] : (o < 128) ? bk[o - 64] : bv[o - 128];
        }
#pragma unroll
        for (int nf = 0; nf < 2; ++nf) {
            const int n = n0 + nf * 16 + l15;
            if (obase < 64) {
                short4 pk;
                pk.x = f2bf((acc[of][nf][0] + bias[0]) * LOG2E);
                pk.y = f2bf((acc[of][nf][1] + bias[1]) * LOG2E);
                pk.z = f2bf((acc[of][nf][2] + bias[2]) * LOG2E);
                pk.w = f2bf((acc[of][nf][3] + bias[3]) * LOG2E);
                *(short4*)(Qt + ((size_t)b * NN + n) * AC2 + obase) = pk;
            } else if (obase < 128) {
                short4 pk;
                pk.x = f2bf(acc[of][nf][0] + bias[0]);
                pk.y = f2bf(acc[of][nf][1] + bias[1]);
                pk.z = f2bf(acc[of][nf][2] + bias[2]);
                pk.w = f2bf(acc[of][nf][3] + bias[3]);
                *(short4*)(Kt + ((size_t)b * NN + n) * AC2 + (obase - 64)) = pk;
            } else {
#pragma unroll
                for (int r = 0; r < 4; ++r) {
                    int o = obase + r - 128;
                    V[(((size_t)b * CC + o) * NN) + n] = f2bf(acc[of][nf][r] + bias[r]);
                }
            }
        }
    }
}

// ---------------- Kernel 2: column softmax stats (base-2 domain) ----------------
// Qt is pre-scaled by log2e -> s' = S*log2e. t' = max' + log2(sum 2^(s'-max')).
__global__ __launch_bounds__(256) void stats_kernel(
    const short* __restrict__ Qt, const short* __restrict__ Kt,
    float* __restrict__ tArr)
{
    const int bid0 = blockIdx.x;                 // grid 1024
    const int xcd = bid0 & 7;
    const int b = xcd >> 1;
    const int j0 = (((xcd & 1) << 7) | (bid0 >> 3)) << 4;
    const int tid = threadIdx.x;
    const int lane = tid & 63, w = tid >> 6;
    const int l15 = lane & 15, lh = lane >> 4;
    const short* Qb = Qt + (size_t)b * NN * AC2;

    bf16x8 Bf[2];
#pragma unroll
    for (int ks = 0; ks < 2; ++ks)
        Bf[ks] = *(const bf16x8*)&Kt[((size_t)b * NN + j0 + l15) * AC2 +
                                     ks * 32 + (lh << 3)];

    bf16x8 A0[4], A1[4];
#pragma unroll
    for (int f = 0; f < 4; ++f) {
        const size_t rowA = (size_t)(w * 1024 + f * 16 + l15);
        A0[f] = *(const bf16x8*)&Qb[rowA * AC2 + (lh << 3)];
        A1[f] = *(const bf16x8*)&Qb[rowA * AC2 + 32 + (lh << 3)];
    }

    float m_run = -INFINITY, l_run = 0.f;
    for (int ii = 0; ii < 16; ++ii) {
        bf16x8 A0n[4], A1n[4];
        const int in0 = w * 1024 + ((ii + 1) & 15) * 64;
#pragma unroll
        for (int f = 0; f < 4; ++f) {
            const size_t rowA = (size_t)(in0 + f * 16 + l15);
            A0n[f] = *(const bf16x8*)&Qb[rowA * AC2 + (lh << 3)];
            A1n[f] = *(const bf16x8*)&Qb[rowA * AC2 + 32 + (lh << 3)];
        }
        f32x4 s[4];
#pragma unroll
        for (int f = 0; f < 4; ++f) {
            f32x4 t = (f32x4){0.f, 0.f, 0.f, 0.f};
            t = __builtin_amdgcn_mfma_f32_16x16x32_bf16(A0[f], Bf[0], t, 0, 0, 0);
            t = __builtin_amdgcn_mfma_f32_16x16x32_bf16(A1[f], Bf[1], t, 0, 0, 0);
            s[f] = t;
        }
        float mx = s[0][0];
#pragma unroll
        for (int f = 0; f < 4; ++f)
#pragma unroll
            for (int r = 0; r < 4; ++r) mx = fmaxf(mx, s[f][r]);
        const float m_new = fmaxf(m_run, mx);
        float add = 0.f;
#pragma unroll
        for (int f = 0; f < 4; ++f)
#pragma unroll
            for (int r = 0; r < 4; ++r) add += exp2f(s[f][r] - m_new);
        l_run = l_run * exp2f(m_run - m_new) + add;
        m_run = m_new;
#pragma unroll
        for (int f = 0; f < 4; ++f) { A0[f] = A0n[f]; A1[f] = A1n[f]; }
    }
#pragma unroll
    for (int off = 16; off <= 32; off <<= 1) {
        float m2 = __shfl_xor(m_run, off);
        float l2 = __shfl_xor(l_run, off);
        float mm = fmaxf(m_run, m2);
        l_run = l_run * exp2f(m_run - mm) + l2 * exp2f(m2 - mm);
        m_run = mm;
    }
    __shared__ float sm[4][16];
    __shared__ float sl[4][16];
    if (lane < 16) { sm[w][lane] = m_run; sl[w][lane] = l_run; }
    __syncthreads();
    if (tid < 16) {
        float m = sm[0][tid], l = sl[0][tid];
#pragma unroll
        for (int q = 1; q < 4; ++q) {
            float m2 = sm[q][tid], l2 = sl[q][tid];
            float mm = fmaxf(m, m2);
            l = l * exp2f(m - mm) + l2 * exp2f(m2 - mm);
            m = mm;
        }
        tArr[(size_t)b * NN + j0 + tid] = m + log2f(l);
    }
}

// ---------------- Kernel 3: partial attention output (templated) ----------------
// ABL==0: real kernel. Swapped QK^T (S^T = mfma(K,Q)): lane's 4 S values are
// consecutive j -> cvt_pk_bf16 + one ds_write_b64 per jf into P^T[i][j].
// P = exp2(s' - t') (base-2 prescale). PV/epilogue identical to R7 (O^T).
// ABL==1: ablation skeleton — same loads/K-staging/S-MFMA/barriers/PV, but
// the S->P->PV data path removed (S asm-sunk, no t, no P writes, no stores).
template<int ABL>
__global__ __launch_bounds__(256, 4) void out_core(
    const short* __restrict__ Qt, const short* __restrict__ Kt,
    const short* __restrict__ V,
    const float* __restrict__ tArr,
    float* __restrict__ out)
{
    __shared__ __align__(16) short Kl[2][64 * PP];   // 18432 B
    __shared__ __align__(16) short Pl[2][64 * PP];   // 18432 B
    const int bid0 = blockIdx.x;                     // grid 1024
    const int xcd = bid0 & 7;
    const int b = xcd >> 1, jh = xcd & 1;
    const int slot = bid0 >> 3;                      // [0,128)
    const int itile = slot >> 1, cs = slot & 1;
    const int i0 = itile << 6, c0 = cs << 7;
    const int jbase = jh << 11;                      // jh * 2048
    const int tid = threadIdx.x;
    const int lane = tid & 63, w = tid >> 6;
    const int l15 = lane & 15, lh = lane >> 4;
    const int iw = i0 + (w << 4);

    const short* Ktb = Kt + (size_t)b * NN * AC2;
    const float* tb  = tArr + (size_t)b * NN + jbase;
    const short* Vb  = V + ((size_t)(b * CC + c0 + (w << 5))) * NN + jbase;

    // K staging roles: thread -> (row, 32B chunk) of the 64x64 tile
    const int krow = tid >> 2, kch = (tid & 3) << 4;
    const short* Ksrc = Ktb + ((size_t)(jbase + krow)) * AC2 + kch;
    short* const KlwA = &Kl[0][krow * PP + kch];
    short* const KlwB = &Kl[1][krow * PP + kch];

    bf16x8 Aq[2];
#pragma unroll
    for (int ks = 0; ks < 2; ++ks)
        Aq[ks] = *(const bf16x8*)&Qt[((size_t)b * NN + iw + l15) * AC2 +
                                     ks * 32 + (lh << 3)];

    f32x4 acc[2][4];   // [cf][f]: O^T tile, col=i, row=c
#pragma unroll
    for (int cf = 0; cf < 2; ++cf)
#pragma unroll
        for (int f = 0; f < 4; ++f) acc[cf][f] = (f32x4){0.f, 0.f, 0.f, 0.f};

    // ---- prologue: K tile 0 -> LDS; issue K tile 1; V/t tile 0 ----
    {
        bf16x8 k0a = *(const bf16x8*)(Ksrc + 0);
        bf16x8 k0b = *(const bf16x8*)(Ksrc + 8);
        *(bf16x8*)(KlwA + 0) = k0a;
        *(bf16x8*)(KlwA + 8) = k0b;
    }
    bf16x8 KpA = *(const bf16x8*)(Ksrc + (1 << 12));
    bf16x8 KpB = *(const bf16x8*)(Ksrc + (1 << 12) + 8);
    bf16x8 Vc[2][2];
#pragma unroll
    for (int cf = 0; cf < 2; ++cf)
#pragma unroll
        for (int ks = 0; ks < 2; ++ks)
            Vc[cf][ks] = *(const bf16x8*)&Vb[(size_t)(cf * 16 + l15) * NN +
                                             ks * 32 + (lh << 3)];
    f32x4 Tc4[4];
    if constexpr (ABL == 0) {
#pragma unroll
        for (int jf = 0; jf < 4; ++jf)
            Tc4[jf] = *(const f32x4*)&tb[jf * 16 + (lh << 2)];
    }
    asm volatile("s_waitcnt lgkmcnt(0)" ::: "memory");
    __builtin_amdgcn_s_barrier();
    asm volatile("" ::: "memory");

    for (int jt = 0; jt < JT; ++jt) {
        const int cur = jt & 1;
        // (1) write K tile jt+1 (regs, in flight since jt-1) into Kl[!cur]
        {
            short* kd = cur ? KlwA : KlwB;
            *(bf16x8*)(kd + 0) = KpA;
            *(bf16x8*)(kd + 8) = KpB;
        }
        // (2) issue K loads for tile jt+2 (wraps harmlessly at loop end)
        {
            const size_t t2 = (size_t)((jt + 2) & (JT - 1)) << 12;
            KpA = *(const bf16x8*)(Ksrc + t2);
            KpB = *(const bf16x8*)(Ksrc + t2 + 8);
        }
        // (3) issue V (+t) loads for tile jt+1
        bf16x8 Vn[2][2];
        f32x4 Tn4[4];
        {
            const int tv = ((jt + 1) & (JT - 1)) << 6;
#pragma unroll
            for (int cf = 0; cf < 2; ++cf)
#pragma unroll
                for (int ks = 0; ks < 2; ++ks)
                    Vn[cf][ks] = *(const bf16x8*)&Vb[(size_t)(cf * 16 + l15) * NN +
                                                     tv + ks * 32 + (lh << 3)];
            if constexpr (ABL == 0) {
#pragma unroll
                for (int jf = 0; jf < 4; ++jf)
                    Tn4[jf] = *(const f32x4*)&tb[tv + jf * 16 + (lh << 2)];
            }
        }
        // (4) S^T phase: mfma(K,Q) -> lane holds 4 consecutive j for i=iw+l15.
        short* Pw = &Pl[cur][0];
#pragma unroll
        for (int jf = 0; jf < 4; ++jf) {
            bf16x8 Ka = *(const bf16x8*)&Kl[cur][(jf * 16 + l15) * PP + (lh << 3)];
            bf16x8 Kb = *(const bf16x8*)&Kl[cur][(jf * 16 + l15) * PP + 32 + (lh << 3)];
            f32x4 s = (f32x4){0.f, 0.f, 0.f, 0.f};
            s = __builtin_amdgcn_mfma_f32_16x16x32_bf16(Ka, Aq[0], s, 0, 0, 0);
            s = __builtin_amdgcn_mfma_f32_16x16x32_bf16(Kb, Aq[1], s, 0, 0, 0);
            if constexpr (ABL == 0) {
                // P^T[i = w*16+l15][j = jf*16 + lh*4 + r], r ascending = j asc.
                float e0 = exp2f(s[0] - Tc4[jf][0]);
                float e1 = exp2f(s[1] - Tc4[jf][1]);
                float e2 = exp2f(s[2] - Tc4[jf][2]);
                float e3 = exp2f(s[3] - Tc4[jf][3]);
                unsigned p01, p23;
                asm volatile("v_cvt_pk_bf16_f32 %0, %1, %2"
                             : "=v"(p01) : "v"(e0), "v"(e1));
                asm volatile("v_cvt_pk_bf16_f32 %0, %1, %2"
                             : "=v"(p23) : "v"(e2), "v"(e3));
                uint2 pk; pk.x = p01; pk.y = p23;
                *(uint2*)&Pw[(w * 16 + l15) * PP + jf * 16 + (lh << 2)] = pk;
            } else {
                asm volatile("" :: "v"(s[0]), "v"(s[1]), "v"(s[2]), "v"(s[3]));
            }
        }
        // lgkm drain + raw barrier (global prefetches stay in flight)
        asm volatile("s_waitcnt lgkmcnt(0)" ::: "memory");
        __builtin_amdgcn_s_barrier();
        asm volatile("" ::: "memory");
        // (5) PV: acc[cf][f] += V-frag x P^T-frag  (O^T tile)
#pragma unroll
        for (int ks = 0; ks < 2; ++ks) {
#pragma unroll
            for (int f = 0; f < 4; ++f) {
                bf16x8 Bp = *(const bf16x8*)&Pw[(f * 16 + l15) * PP +
                                                ks * 32 + (lh << 3)];
#pragma unroll
                for (int cf = 0; cf < 2; ++cf)
                    acc[cf][f] = __builtin_amdgcn_mfma_f32_16x16x32_bf16(
                        Vc[cf][ks], Bp, acc[cf][f], 0, 0, 0);
            }
        }
        // rotate prefetch regs
#pragma unroll
        for (int cf = 0; cf < 2; ++cf) {
            Vc[cf][0] = Vn[cf][0]; Vc[cf][1] = Vn[cf][1];
        }
        if constexpr (ABL == 0) {
#pragma unroll
            for (int jf = 0; jf < 4; ++jf) Tc4[jf] = Tn4[jf];
        }
    }

    if constexpr (ABL == 0) {
        // epilogue: acc = O^T (c rows, i cols) -> coalesced partial bf16 halves
        unsigned short* po = (unsigned short*)out;
#pragma unroll
        for (int cf = 0; cf < 2; ++cf) {
#pragma unroll
            for (int r = 0; r < 4; ++r) {
                const int c = c0 + (w << 5) + cf * 16 + (lh << 2) + r;
#pragma unroll
                for (int f = 0; f < 4; ++f) {
                    const size_t gi = ((size_t)(b * CC + c)) * NN + i0 + f * 16 + l15;
                    po[gi * 2 + jh] = (unsigned short)f2bf(acc[cf][f][r]);
                }
            }
        }
    } else {
        float sink = 0.f;
#pragma unroll
        for (int cf = 0; cf < 2; ++cf)
#pragma unroll
            for (int f = 0; f < 4; ++f)
#pragma unroll
                for (int r = 0; r < 4; ++r) sink += acc[cf][f][r];
        asm volatile("" :: "v"(sink));
    }
}

// ---------------- Kernel 4: combine halves + gamma + residual ----------------
__global__ __launch_bounds__(256) void reduce_kernel(
    const float* __restrict__ x, const float* __restrict__ gamma,
    float* __restrict__ out)
{
    const float g = gamma[0];
    const size_t total = (size_t)BB * CC * NN / 4;   // float4 groups
    for (size_t i = (size_t)blockIdx.x * 256 + threadIdx.x; i < total;
         i += (size_t)2048 * 256) {
        uint4 pv = ((const uint4*)out)[i];
        float4 xv = ((const float4*)x)[i];
        float4 o;
        o.x = g * (bf2f(pv.x & 0xFFFFu) + bf2f(pv.x >> 16)) + xv.x;
        o.y = g * (bf2f(pv.y & 0xFFFFu) + bf2f(pv.y >> 16)) + xv.y;
        o.z = g * (bf2f(pv.z & 0xFFFFu) + bf2f(pv.z >> 16)) + xv.z;
        o.w = g * (bf2f(pv.w & 0xFFFFu) + bf2f(pv.w >> 16)) + xv.w;
        ((float4*)out)[i] = o;
    }
}

extern "C" void kernel_launch(void* const* d_in, const int* in_sizes, int n_in,
                              void* d_out, int out_size, void* d_ws, size_t ws_size,
                              hipStream_t stream) {
    const float* x     = (const float*)d_in[0];
    const float* Wq    = (const float*)d_in[1];
    const float* bq    = (const float*)d_in[2];
    const float* Wk    = (const float*)d_in[3];
    const float* bk    = (const float*)d_in[4];
    const float* Wv    = (const float*)d_in[5];
    const float* bv    = (const float*)d_in[6];
    const float* gamma = (const float*)d_in[7];
    float* out = (float*)d_out;

    short* Qt = (short*)d_ws;                            // [B][N][64] bf16 (2 MB)
    short* Kt = Qt + (size_t)BB * NN * AC2;              // [B][N][64] bf16 (2 MB)
    short* V  = Kt + (size_t)BB * NN * AC2;              // [B][C][N]  bf16 (8 MB)
    float* tArr = (float*)(V + (size_t)BB * CC * NN);    // [B][N]     f32  (64 KB)
    short* Wb = (short*)(tArr + (size_t)BB * NN);        // [384][256] bf16 (192 KB)

    prep_kernel<<<96, 256, 0, stream>>>(Wq, Wk, Wv, Wb);
    qkv_kernel<<<BB * 128, 512, 0, stream>>>(x, Wb, bq, bk, bv, Qt, Kt, V);
    stats_kernel<<<BB * 256, 256, 0, stream>>>(Qt, Kt, tArr);
    out_core<0><<<BB * 256, 256, 0, stream>>>(Qt, Kt, V, tArr, out);
    reduce_kernel<<<2048, 256, 0, stream>>>(x, gamma, out);
    // ablation dispatch (results discarded; measures the skeleton floor)
    out_core<1><<<BB * 256, 256, 0, stream>>>(Qt, Kt, V, tArr, out);
}

// Round 10
// 343.011 us; speedup vs baseline: 1.0465x; 1.0465x over previous
//
#include <hip/hip_runtime.h>
#include <hip/hip_bf16.h>

#define BB 4
#define CC 256
#define NN 4096
#define AC2 64
#define PP 76   // LDS pitch (shorts): 152 B rows -> bank-stride 6 (gcd 2) = conflict-free
#define JT 32   // j-tiles per out-block (j-split 2)
#define LOG2E 1.4426950408889634f

typedef __attribute__((ext_vector_type(4))) float f32x4;
typedef __attribute__((ext_vector_type(8))) short bf16x8;

__device__ __forceinline__ short f2bf(float f) {
    unsigned u = __builtin_bit_cast(unsigned, f);
    u = u + 0x7FFFu + ((u >> 16) & 1u);
    return (short)(u >> 16);
}
__device__ __forceinline__ float bf2f(unsigned short h) {
    unsigned u = ((unsigned)h) << 16;
    return __builtin_bit_cast(float, u);
}

// ---------------- Kernel 0: convert weights to bf16 Wb[384][256] ----------------
__global__ __launch_bounds__(256) void prep_kernel(
    const float* __restrict__ Wq, const float* __restrict__ Wk,
    const float* __restrict__ Wv, short* __restrict__ Wb)
{
    const int idx = (blockIdx.x * 256 + threadIdx.x) * 4;  // 96 blocks cover 98304
    const int o = idx >> 8, c = idx & 255;
    const float* row = (o < 64) ? (Wq + o * CC)
                     : (o < 128) ? (Wk + (o - 64) * CC)
                                 : (Wv + (o - 128) * CC);
    float4 v = *(const float4*)&row[c];
    short4 s4;
    s4.x = f2bf(v.x); s4.y = f2bf(v.y); s4.z = f2bf(v.z); s4.w = f2bf(v.w);
    *(short4*)&Wb[idx] = s4;
}

// ---------------- Kernel 1: QKV projection ----------------
// Q outputs (o<64) scaled by log2e so downstream softmax uses exp2 directly.
__global__ __launch_bounds__(512) void qkv_kernel(
    const float* __restrict__ x, const short* __restrict__ Wb,
    const float* __restrict__ bq, const float* __restrict__ bk,
    const float* __restrict__ bv,
    short* __restrict__ Qt, short* __restrict__ Kt, short* __restrict__ V)
{
    __shared__ __align__(16) short Xl[32 * 72];
    const int bid0 = blockIdx.x;                 // grid 512
    const int xcd = bid0 & 7;
    const int b = xcd >> 1, nh = xcd & 1;
    const int n0 = (nh * 64 + (bid0 >> 3)) << 5; // n-tile of 32
    const int tid = threadIdx.x;
    const int lane = tid & 63, w = tid >> 6;
    const int l15 = lane & 15, lh = lane >> 4;

    f32x4 acc[3][2];
#pragma unroll
    for (int i = 0; i < 3; ++i)
#pragma unroll
        for (int j = 0; j < 2; ++j) acc[i][j] = (f32x4){0.f, 0.f, 0.f, 0.f};

    for (int ck = 0; ck < 4; ++ck) {
        const int c0 = ck << 6;
        bf16x8 Af[3][2];
#pragma unroll
        for (int of = 0; of < 3; ++of)
#pragma unroll
            for (int ks = 0; ks < 2; ++ks)
                Af[of][ks] = *(const bf16x8*)&Wb[(size_t)(w * 48 + of * 16 + l15) * CC +
                                                 c0 + ks * 32 + (lh << 3)];
        {
            const int cr = tid >> 3, q4 = tid & 7;
            float4 v = *(const float4*)&x[((size_t)(b * CC + c0 + cr)) * NN + n0 + q4 * 4];
            Xl[(q4 * 4 + 0) * 72 + cr] = f2bf(v.x);
            Xl[(q4 * 4 + 1) * 72 + cr] = f2bf(v.y);
            Xl[(q4 * 4 + 2) * 72 + cr] = f2bf(v.z);
            Xl[(q4 * 4 + 3) * 72 + cr] = f2bf(v.w);
        }
        __syncthreads();
#pragma unroll
        for (int ks = 0; ks < 2; ++ks) {
            const int co = ks * 32 + (lh << 3);
            bf16x8 Bf[2];
#pragma unroll
            for (int nf = 0; nf < 2; ++nf)
                Bf[nf] = *(const bf16x8*)&Xl[(nf * 16 + l15) * 72 + co];
#pragma unroll
            for (int of = 0; of < 3; ++of)
#pragma unroll
                for (int nf = 0; nf < 2; ++nf)
                    acc[of][nf] = __builtin_amdgcn_mfma_f32_16x16x32_bf16(
                        Af[of][ks], Bf[nf], acc[of][nf], 0, 0, 0);
        }
        __syncthreads();
    }
#pragma unroll
    for (int of = 0; of < 3; ++of) {
        const int obase = w * 48 + of * 16 + (lh << 2);
        float bias[4];
#pragma unroll
        for (int r = 0; r < 4; ++r) {
            int o = obase + r;
            bias[r] = (o < 64) ? bq[o] : (o < 128) ? bk[o - 64] : bv[o - 128];
        }
#pragma unroll
        for (int nf = 0; nf < 2; ++nf) {
            const int n = n0 + nf * 16 + l15;
            if (obase < 64) {
                short4 pk;
                pk.x = f2bf((acc[of][nf][0] + bias[0]) * LOG2E);
                pk.y = f2bf((acc[of][nf][1] + bias[1]) * LOG2E);
                pk.z = f2bf((acc[of][nf][2] + bias[2]) * LOG2E);
                pk.w = f2bf((acc[of][nf][3] + bias[3]) * LOG2E);
                *(short4*)(Qt + ((size_t)b * NN + n) * AC2 + obase) = pk;
            } else if (obase < 128) {
                short4 pk;
                pk.x = f2bf(acc[of][nf][0] + bias[0]);
                pk.y = f2bf(acc[of][nf][1] + bias[1]);
                pk.z = f2bf(acc[of][nf][2] + bias[2]);
                pk.w = f2bf(acc[of][nf][3] + bias[3]);
                *(short4*)(Kt + ((size_t)b * NN + n) * AC2 + (obase - 64)) = pk;
            } else {
#pragma unroll
                for (int r = 0; r < 4; ++r) {
                    int o = obase + r - 128;
                    V[(((size_t)b * CC + o) * NN) + n] = f2bf(acc[of][nf][r] + bias[r]);
                }
            }
        }
    }
}

// ---------------- Kernel 2: column softmax stats (base-2 domain) ----------------
__global__ __launch_bounds__(256) void stats_kernel(
    const short* __restrict__ Qt, const short* __restrict__ Kt,
    float* __restrict__ tArr)
{
    const int bid0 = blockIdx.x;                 // grid 1024
    const int xcd = bid0 & 7;
    const int b = xcd >> 1;
    const int j0 = (((xcd & 1) << 7) | (bid0 >> 3)) << 4;
    const int tid = threadIdx.x;
    const int lane = tid & 63, w = tid >> 6;
    const int l15 = lane & 15, lh = lane >> 4;
    const short* Qb = Qt + (size_t)b * NN * AC2;

    bf16x8 Bf[2];
#pragma unroll
    for (int ks = 0; ks < 2; ++ks)
        Bf[ks] = *(const bf16x8*)&Kt[((size_t)b * NN + j0 + l15) * AC2 +
                                     ks * 32 + (lh << 3)];

    bf16x8 A0[4], A1[4];
#pragma unroll
    for (int f = 0; f < 4; ++f) {
        const size_t rowA = (size_t)(w * 1024 + f * 16 + l15);
        A0[f] = *(const bf16x8*)&Qb[rowA * AC2 + (lh << 3)];
        A1[f] = *(const bf16x8*)&Qb[rowA * AC2 + 32 + (lh << 3)];
    }

    float m_run = -INFINITY, l_run = 0.f;
    for (int ii = 0; ii < 16; ++ii) {
        bf16x8 A0n[4], A1n[4];
        const int in0 = w * 1024 + ((ii + 1) & 15) * 64;
#pragma unroll
        for (int f = 0; f < 4; ++f) {
            const size_t rowA = (size_t)(in0 + f * 16 + l15);
            A0n[f] = *(const bf16x8*)&Qb[rowA * AC2 + (lh << 3)];
            A1n[f] = *(const bf16x8*)&Qb[rowA * AC2 + 32 + (lh << 3)];
        }
        f32x4 s[4];
#pragma unroll
        for (int f = 0; f < 4; ++f) {
            f32x4 t = (f32x4){0.f, 0.f, 0.f, 0.f};
            t = __builtin_amdgcn_mfma_f32_16x16x32_bf16(A0[f], Bf[0], t, 0, 0, 0);
            t = __builtin_amdgcn_mfma_f32_16x16x32_bf16(A1[f], Bf[1], t, 0, 0, 0);
            s[f] = t;
        }
        float mx = s[0][0];
#pragma unroll
        for (int f = 0; f < 4; ++f)
#pragma unroll
            for (int r = 0; r < 4; ++r) mx = fmaxf(mx, s[f][r]);
        const float m_new = fmaxf(m_run, mx);
        float add = 0.f;
#pragma unroll
        for (int f = 0; f < 4; ++f)
#pragma unroll
            for (int r = 0; r < 4; ++r) add += exp2f(s[f][r] - m_new);
        l_run = l_run * exp2f(m_run - m_new) + add;
        m_run = m_new;
#pragma unroll
        for (int f = 0; f < 4; ++f) { A0[f] = A0n[f]; A1[f] = A1n[f]; }
    }
#pragma unroll
    for (int off = 16; off <= 32; off <<= 1) {
        float m2 = __shfl_xor(m_run, off);
        float l2 = __shfl_xor(l_run, off);
        float mm = fmaxf(m_run, m2);
        l_run = l_run * exp2f(m_run - mm) + l2 * exp2f(m2 - mm);
        m_run = mm;
    }
    __shared__ float sm[4][16];
    __shared__ float sl[4][16];
    if (lane < 16) { sm[w][lane] = m_run; sl[w][lane] = l_run; }
    __syncthreads();
    if (tid < 16) {
        float m = sm[0][tid], l = sl[0][tid];
#pragma unroll
        for (int q = 1; q < 4; ++q) {
            float m2 = sm[q][tid], l2 = sl[q][tid];
            float mm = fmaxf(m, m2);
            l = l * exp2f(m - mm) + l2 * exp2f(m2 - mm);
            m = mm;
        }
        tArr[(size_t)b * NN + j0 + tid] = m + log2f(l);
    }
}

// ---------------- Kernel 3: partial attention output ----------------
// XCD-pinned (xcd = b*2+jh). K: 2-deep register prefetch -> double-buffered
// LDS (the only prefetch that keeps registers). t and V: JIT loads from
// XCD-hot L2 (4 independent blocks/CU hide the latency; avoids the R9
// register-sink/spill disease). Swapped QK^T (S^T=mfma(K,Q)) -> cvt_pk +
// one ds_write_b64 per jf. PV wrapped in s_setprio (T5). Partial O written
// as bf16 byte-halves of d_out (jh=0 low, jh=1 high).
__global__ __launch_bounds__(256, 4) void out_core(
    const short* __restrict__ Qt, const short* __restrict__ Kt,
    const short* __restrict__ V,
    const float* __restrict__ tArr,
    float* __restrict__ out)
{
    __shared__ __align__(16) short Kl[2][64 * PP];   // 19456 B
    __shared__ __align__(16) short Pl[2][64 * PP];   // 19456 B
    const int bid0 = blockIdx.x;                     // grid 1024
    const int xcd = bid0 & 7;
    const int b = xcd >> 1, jh = xcd & 1;
    const int slot = bid0 >> 3;                      // [0,128)
    const int itile = slot >> 1, cs = slot & 1;
    const int i0 = itile << 6, c0 = cs << 7;
    const int jbase = jh << 11;                      // jh * 2048
    const int tid = threadIdx.x;
    const int lane = tid & 63, w = tid >> 6;
    const int l15 = lane & 15, lh = lane >> 4;
    const int iw = i0 + (w << 4);

    const short* Ktb = Kt + (size_t)b * NN * AC2;
    const float* tb  = tArr + (size_t)b * NN + jbase;
    const short* Vb  = V + ((size_t)(b * CC + c0 + (w << 5))) * NN + jbase;

    // K staging roles: thread -> (row, 32B chunk) of the 64x64 tile
    const int krow = tid >> 2, kch = (tid & 3) << 4;
    const short* Ksrc = Ktb + ((size_t)(jbase + krow)) * AC2 + kch;
    short* const KlwA = &Kl[0][krow * PP + kch];
    short* const KlwB = &Kl[1][krow * PP + kch];

    bf16x8 Aq[2];
#pragma unroll
    for (int ks = 0; ks < 2; ++ks)
        Aq[ks] = *(const bf16x8*)&Qt[((size_t)b * NN + iw + l15) * AC2 +
                                     ks * 32 + (lh << 3)];

    f32x4 acc[2][4];   // [cf][f]: O^T tile, col=i, row=c
#pragma unroll
    for (int cf = 0; cf < 2; ++cf)
#pragma unroll
        for (int f = 0; f < 4; ++f) acc[cf][f] = (f32x4){0.f, 0.f, 0.f, 0.f};

    // ---- prologue: K tile 0 -> LDS; issue K tile 1 ----
    {
        bf16x8 k0a = *(const bf16x8*)(Ksrc + 0);
        bf16x8 k0b = *(const bf16x8*)(Ksrc + 8);
        *(bf16x8*)(KlwA + 0) = k0a;
        *(bf16x8*)(KlwA + 8) = k0b;
    }
    bf16x8 KpA = *(const bf16x8*)(Ksrc + (1 << 12));
    bf16x8 KpB = *(const bf16x8*)(Ksrc + (1 << 12) + 8);
    asm volatile("s_waitcnt lgkmcnt(0)" ::: "memory");
    __builtin_amdgcn_s_barrier();
    asm volatile("" ::: "memory");

    for (int jt = 0; jt < JT; ++jt) {
        const int cur = jt & 1;
        const int jb = jt << 6;
        // (1) write K tile jt+1 (regs, in flight since jt-1) into Kl[!cur]
        {
            short* kd = cur ? KlwA : KlwB;
            *(bf16x8*)(kd + 0) = KpA;
            *(bf16x8*)(kd + 8) = KpB;
        }
        // (2) issue K loads for tile jt+2 (wraps harmlessly at loop end)
        {
            const size_t t2 = (size_t)((jt + 2) & (JT - 1)) << 12;
            KpA = *(const bf16x8*)(Ksrc + t2);
            KpB = *(const bf16x8*)(Ksrc + t2 + 8);
        }
        // (3) S^T phase: mfma(K,Q) -> lane holds 4 consecutive j for i=iw+l15;
        //     t loaded JIT (L2-hot, f32x4 matches the lane's 4 j's exactly).
        short* Pw = &Pl[cur][0];
#pragma unroll
        for (int jf = 0; jf < 4; ++jf) {
            bf16x8 Ka = *(const bf16x8*)&Kl[cur][(jf * 16 + l15) * PP + (lh << 3)];
            bf16x8 Kb = *(const bf16x8*)&Kl[cur][(jf * 16 + l15) * PP + 32 + (lh << 3)];
            f32x4 tj = *(const f32x4*)&tb[jb + jf * 16 + (lh << 2)];
            f32x4 s = (f32x4){0.f, 0.f, 0.f, 0.f};
            s = __builtin_amdgcn_mfma_f32_16x16x32_bf16(Ka, Aq[0], s, 0, 0, 0);
            s = __builtin_amdgcn_mfma_f32_16x16x32_bf16(Kb, Aq[1], s, 0, 0, 0);
            // P^T[i = w*16+l15][j = jf*16 + lh*4 + r], r ascending = j ascending
            float e0 = exp2f(s[0] - tj[0]);
            float e1 = exp2f(s[1] - tj[1]);
            float e2 = exp2f(s[2] - tj[2]);
            float e3 = exp2f(s[3] - tj[3]);
            unsigned p01, p23;
            asm volatile("v_cvt_pk_bf16_f32 %0, %1, %2"
                         : "=v"(p01) : "v"(e0), "v"(e1));
            asm volatile("v_cvt_pk_bf16_f32 %0, %1, %2"
                         : "=v"(p23) : "v"(e2), "v"(e3));
            uint2 pk; pk.x = p01; pk.y = p23;
            *(uint2*)&Pw[(w * 16 + l15) * PP + jf * 16 + (lh << 2)] = pk;
        }
        // lgkm drain + raw barrier (K global prefetch stays in flight)
        asm volatile("s_waitcnt lgkmcnt(0)" ::: "memory");
        __builtin_amdgcn_s_barrier();
        asm volatile("" ::: "memory");
        // (4) PV: V frags JIT from L2; acc[cf][f] += V x P^T (O^T tile)
        __builtin_amdgcn_s_setprio(1);
#pragma unroll
        for (int ks = 0; ks < 2; ++ks) {
            bf16x8 Vc[2];
#pragma unroll
            for (int cf = 0; cf < 2; ++cf)
                Vc[cf] = *(const bf16x8*)&Vb[(size_t)(cf * 16 + l15) * NN +
                                             jb + ks * 32 + (lh << 3)];
#pragma unroll
            for (int f = 0; f < 4; ++f) {
                bf16x8 Bp = *(const bf16x8*)&Pw[(f * 16 + l15) * PP +
                                                ks * 32 + (lh << 3)];
#pragma unroll
                for (int cf = 0; cf < 2; ++cf)
                    acc[cf][f] = __builtin_amdgcn_mfma_f32_16x16x32_bf16(
                        Vc[cf], Bp, acc[cf][f], 0, 0, 0);
            }
        }
        __builtin_amdgcn_s_setprio(0);
    }

    // ---- epilogue: acc = O^T (c rows, i cols) -> coalesced partial bf16 halves
    unsigned short* po = (unsigned short*)out;
#pragma unroll
    for (int cf = 0; cf < 2; ++cf) {
#pragma unroll
        for (int r = 0; r < 4; ++r) {
            const int c = c0 + (w << 5) + cf * 16 + (lh << 2) + r;
#pragma unroll
            for (int f = 0; f < 4; ++f) {
                const size_t gi = ((size_t)(b * CC + c)) * NN + i0 + f * 16 + l15;
                po[gi * 2 + jh] = (unsigned short)f2bf(acc[cf][f][r]);
            }
        }
    }
}

// ---------------- Kernel 4: combine halves + gamma + residual ----------------
__global__ __launch_bounds__(256) void reduce_kernel(
    const float* __restrict__ x, const float* __restrict__ gamma,
    float* __restrict__ out)
{
    const float g = gamma[0];
    const size_t total = (size_t)BB * CC * NN / 4;   // float4 groups
    for (size_t i = (size_t)blockIdx.x * 256 + threadIdx.x; i < total;
         i += (size_t)2048 * 256) {
        uint4 pv = ((const uint4*)out)[i];
        float4 xv = ((const float4*)x)[i];
        float4 o;
        o.x = g * (bf2f(pv.x & 0xFFFFu) + bf2f(pv.x >> 16)) + xv.x;
        o.y = g * (bf2f(pv.y & 0xFFFFu) + bf2f(pv.y >> 16)) + xv.y;
        o.z = g * (bf2f(pv.z & 0xFFFFu) + bf2f(pv.z >> 16)) + xv.z;
        o.w = g * (bf2f(pv.w & 0xFFFFu) + bf2f(pv.w >> 16)) + xv.w;
        ((float4*)out)[i] = o;
    }
}

extern "C" void kernel_launch(void* const* d_in, const int* in_sizes, int n_in,
                              void* d_out, int out_size, void* d_ws, size_t ws_size,
                              hipStream_t stream) {
    const float* x     = (const float*)d_in[0];
    const float* Wq    = (const float*)d_in[1];
    const float* bq    = (const float*)d_in[2];
    const float* Wk    = (const float*)d_in[3];
    const float* bk    = (const float*)d_in[4];
    const float* Wv    = (const float*)d_in[5];
    const float* bv    = (const float*)d_in[6];
    const float* gamma = (const float*)d_in[7];
    float* out = (float*)d_out;

    short* Qt = (short*)d_ws;                            // [B][N][64] bf16 (2 MB)
    short* Kt = Qt + (size_t)BB * NN * AC2;              // [B][N][64] bf16 (2 MB)
    short* V  = Kt + (size_t)BB * NN * AC2;              // [B][C][N]  bf16 (8 MB)
    float* tArr = (float*)(V + (size_t)BB * CC * NN);    // [B][N]     f32  (64 KB)
    short* Wb = (short*)(tArr + (size_t)BB * NN);        // [384][256] bf16 (192 KB)

    prep_kernel<<<96, 256, 0, stream>>>(Wq, Wk, Wv, Wb);
    qkv_kernel<<<BB * 128, 512, 0, stream>>>(x, Wb, bq, bk, bv, Qt, Kt, V);
    stats_kernel<<<BB * 256, 256, 0, stream>>>(Qt, Kt, tArr);
    out_core<<<BB * 256, 256, 0, stream>>>(Qt, Kt, V, tArr, out);
    reduce_kernel<<<2048, 256, 0, stream>>>(x, gamma, out);
}